// Round 2
// baseline (488.651 us; speedup 1.0000x reference)
//
#include <hip/hip_runtime.h>

// Problem constants
#define N_    4
#define C_    256
#define PS_   4096      // 64*64 source pixels
#define PO_   16384     // 128*128 output pixels
#define COMP_ 64
#define QCH_  100       // K*K*R*R
#define KK_   25

// ---------------------------------------------------------------------------
// Kernel 0: W_eff[o,c] = sum_m w_bott[o,m]*w_conv2[m,c] + w_bott[o,256+c]
//           b_eff[o]   = sum_m w_bott[o,m]*b_conv2[m]
__global__ void k_weff(const float* __restrict__ w_bott, const float* __restrict__ w_conv2,
                       const float* __restrict__ b_conv2, float* __restrict__ Weff,
                       float* __restrict__ beff) {
    int o = blockIdx.x, c = threadIdx.x;
    __shared__ float wb[512];
    wb[c]       = w_bott[o * 512 + c];
    wb[c + 256] = w_bott[o * 512 + 256 + c];
    __syncthreads();
    float acc = wb[256 + c];
    #pragma unroll 8
    for (int m = 0; m < 256; ++m)
        acc += wb[m] * w_conv2[m * 256 + c];
    Weff[o * 256 + c] = acc;
    if (c == 0) {
        float be = 0.f;
        for (int m = 0; m < 256; ++m) be += wb[m] * b_conv2[m];
        beff[o] = be;
    }
}

// ---------------------------------------------------------------------------
// Kernel 1: channel compressor 1x1: comp[n,m,p] = sum_c w_cc[m,c]*x[n,c,p]+b_cc[m]
__global__ void k_compress(const float* __restrict__ x, const float* __restrict__ w_cc,
                           const float* __restrict__ b_cc, float* __restrict__ comp) {
    int n = blockIdx.z, m0 = blockIdx.y * 16, px = blockIdx.x * 256 + threadIdx.x;
    __shared__ float wl[16 * 256];
    for (int i = threadIdx.x; i < 16 * 256; i += 256)
        wl[i] = w_cc[(m0 + (i >> 8)) * 256 + (i & 255)];
    __syncthreads();
    float acc[16];
    #pragma unroll
    for (int m = 0; m < 16; ++m) acc[m] = b_cc[m0 + m];
    const float* xb = x + n * C_ * PS_ + px;
    for (int c0 = 0; c0 < 256; c0 += 8) {
        float xv[8];
        #pragma unroll
        for (int cc = 0; cc < 8; ++cc) xv[cc] = xb[(c0 + cc) * PS_];
        #pragma unroll
        for (int m = 0; m < 16; ++m) {
            #pragma unroll
            for (int cc = 0; cc < 8; ++cc)
                acc[m] += wl[m * 256 + c0 + cc] * xv[cc];
        }
    }
    float* cp = comp + (n * COMP_ + m0) * PS_ + px;
    #pragma unroll
    for (int m = 0; m < 16; ++m) cp[m * PS_] = acc[m];
}

// ---------------------------------------------------------------------------
// Kernel 2: content encoder 3x3 (pad 1): mask_raw[n,q,y,x], q<100
// grid 256 = (n, 8x8 tiles of 8x8 px); threads 256 = 4 q-groups x 64 px
__global__ void k_encode(const float* __restrict__ comp, const float* __restrict__ w_ce,
                         const float* __restrict__ b_ce, float* __restrict__ mask_raw) {
    int b = blockIdx.x;
    int n = b >> 6, tile = b & 63;
    int ty0 = (tile >> 3) << 3, tx0 = (tile & 7) << 3;
    int tid = threadIdx.x;
    int g = tid >> 6, px = tid & 63;
    int sy = px >> 3, sx = px & 7;
    int q0 = g * 25;
    __shared__ float ct[8 * 100];   // 8 channels x 10x10 tile
    __shared__ float wl[8 * 900];   // 8 channels x 100 q x 9 taps
    float acc[25];
    #pragma unroll
    for (int q = 0; q < 25; ++q) acc[q] = b_ce[q0 + q];
    for (int cg = 0; cg < 8; ++cg) {
        __syncthreads();
        for (int idx = tid; idx < 800; idx += 256) {
            int cc = idx / 100, r = idx - cc * 100;
            int yy = ty0 - 1 + r / 10, xx = tx0 - 1 + (r % 10);
            float v = 0.f;
            if (yy >= 0 && yy < 64 && xx >= 0 && xx < 64)
                v = comp[(n * COMP_ + cg * 8 + cc) * PS_ + yy * 64 + xx];
            ct[idx] = v;
        }
        for (int idx = tid; idx < 7200; idx += 256) {
            int cc = idx / 900, r = idx - cc * 900;
            int q = r / 9, t = r - q * 9;
            wl[idx] = w_ce[(q * COMP_ + cg * 8 + cc) * 9 + t];
        }
        __syncthreads();
        for (int c = 0; c < 8; ++c) {
            float nb[9];
            const float* cb = ct + c * 100 + sy * 10 + sx;
            #pragma unroll
            for (int dy = 0; dy < 3; ++dy) {
                #pragma unroll
                for (int dx = 0; dx < 3; ++dx)
                    nb[dy * 3 + dx] = cb[dy * 10 + dx];
            }
            const float* wbp = wl + c * 900 + q0 * 9;
            #pragma unroll
            for (int q = 0; q < 25; ++q) {
                #pragma unroll
                for (int t = 0; t < 9; ++t)
                    acc[q] += wbp[q * 9 + t] * nb[t];
            }
        }
    }
    float* mp = mask_raw + (n * QCH_ + q0) * PS_ + (ty0 + sy) * 64 + (tx0 + sx);
    #pragma unroll
    for (int q = 0; q < 25; ++q) mp[q * PS_] = acc[q];
}

// ---------------------------------------------------------------------------
// Kernel 3: Y[n,o,p] = sum_c Weff[o,c]*high[n,c,p]  (64x64 grid GEMM, no bias)
__global__ void k_ygemm(const float* __restrict__ Weff, const float* __restrict__ high,
                        float* __restrict__ Y) {
    int n = blockIdx.z, o0 = blockIdx.y * 64, p0 = blockIdx.x * 64;
    int tid = threadIdx.x;
    int tyy = tid >> 4, txx = tid & 15;
    __shared__ float As[16][68];   // [k][o], padded
    __shared__ float Bs[16][64];   // [k][p]
    float acc[4][4] = {};
    for (int k0 = 0; k0 < 256; k0 += 16) {
        __syncthreads();
        #pragma unroll
        for (int j = 0; j < 4; ++j) {
            int idx = tid + j * 256;
            int oo = idx >> 4, kk = idx & 15;
            As[kk][oo] = Weff[(o0 + oo) * 256 + k0 + kk];
            int kb = idx >> 6, pp = idx & 63;
            Bs[kb][pp] = high[(n * C_ + k0 + kb) * PS_ + p0 + pp];
        }
        __syncthreads();
        #pragma unroll
        for (int kk = 0; kk < 16; ++kk) {
            float4 a = *reinterpret_cast<const float4*>(&As[kk][tyy * 4]);
            float4 bv = *reinterpret_cast<const float4*>(&Bs[kk][txx * 4]);
            acc[0][0] += a.x * bv.x; acc[0][1] += a.x * bv.y; acc[0][2] += a.x * bv.z; acc[0][3] += a.x * bv.w;
            acc[1][0] += a.y * bv.x; acc[1][1] += a.y * bv.y; acc[1][2] += a.y * bv.z; acc[1][3] += a.y * bv.w;
            acc[2][0] += a.z * bv.x; acc[2][1] += a.z * bv.y; acc[2][2] += a.z * bv.z; acc[2][3] += a.z * bv.w;
            acc[3][0] += a.w * bv.x; acc[3][1] += a.w * bv.y; acc[3][2] += a.w * bv.z; acc[3][3] += a.w * bv.w;
        }
    }
    #pragma unroll
    for (int ii = 0; ii < 4; ++ii) {
        float4 r; r.x = acc[ii][0]; r.y = acc[ii][1]; r.z = acc[ii][2]; r.w = acc[ii][3];
        *reinterpret_cast<float4*>(Y + (n * C_ + o0 + tyy * 4 + ii) * PS_ + p0 + txx * 4) = r;
    }
}

// ---------------------------------------------------------------------------
// Kernel 4: softmax(25) masks + CARAFE reassembly of Y -> x_pre (d_out, f32)
// grid 256 = (n, 8x8 source tile); threads 256 = 16x16 output pixels
__global__ void k_carafe(const float* __restrict__ Y, const float* __restrict__ mask_raw,
                         const float* __restrict__ beff, float* __restrict__ xout) {
    int b = blockIdx.x;
    int n = b >> 6, tile = b & 63;
    int sh0 = (tile >> 3) << 3, sw0 = (tile & 7) << 3;
    int tid = threadIdx.x;
    int ty = tid >> 4, tx = tid & 15;
    int oi = sh0 * 2 + ty, oj = sw0 * 2 + tx;
    int h = sh0 + (ty >> 1), w = sw0 + (tx >> 1);
    int sub = ((ty & 1) << 1) | (tx & 1);
    float v[25];
    const float* mp = mask_raw + n * QCH_ * PS_ + h * 64 + w;
    #pragma unroll
    for (int k = 0; k < 25; ++k) v[k] = mp[(k * 4 + sub) * PS_];
    float mx = v[0];
    #pragma unroll
    for (int k = 1; k < 25; ++k) mx = fmaxf(mx, v[k]);
    float s = 0.f;
    #pragma unroll
    for (int k = 0; k < 25; ++k) { v[k] = __expf(v[k] - mx); s += v[k]; }
    float inv = 1.f / s;
    #pragma unroll
    for (int k = 0; k < 25; ++k) v[k] *= inv;

    __shared__ float xt[32 * 144];   // 32 channels x 12x12 halo tile of Y
    int sy = ty >> 1, sx = tx >> 1;
    float* hp = xout + n * C_ * PO_ + oi * 128 + oj;
    for (int cg = 0; cg < 8; ++cg) {
        __syncthreads();
        for (int idx = tid; idx < 4608; idx += 256) {
            int cc = idx / 144, r = idx - cc * 144;
            int yy = sh0 - 2 + r / 12, xx = sw0 - 2 + (r % 12);
            float val = 0.f;
            if (yy >= 0 && yy < 64 && xx >= 0 && xx < 64)
                val = Y[(n * C_ + cg * 32 + cc) * PS_ + yy * 64 + xx];
            xt[idx] = val;
        }
        __syncthreads();
        for (int cc = 0; cc < 32; ++cc) {
            const float* base = xt + cc * 144 + sy * 12 + sx;
            float acc = beff[cg * 32 + cc];
            #pragma unroll
            for (int ky = 0; ky < 5; ++ky) {
                #pragma unroll
                for (int kx = 0; kx < 5; ++kx)
                    acc += v[ky * 5 + kx] * base[ky * 12 + kx];
            }
            hp[(cg * 32 + cc) * PO_] = acc;
        }
    }
}

// ---------------------------------------------------------------------------
// Kernel 5: per-channel BN stats -> scale/shift. One block per channel.
__global__ void k_stats(const float* __restrict__ xb, const float* __restrict__ gamma,
                        const float* __restrict__ beta, float* __restrict__ scale,
                        float* __restrict__ shift) {
    int o = blockIdx.x, tid = threadIdx.x;
    float s = 0.f, s2 = 0.f;
    for (int n = 0; n < 4; ++n) {
        const float* p = xb + (n * C_ + o) * PO_;
        #pragma unroll 4
        for (int i = 0; i < 64; ++i) {
            float v = p[i * 256 + tid];
            s += v; s2 += v * v;
        }
    }
    __shared__ float rs[256], rq[256];
    rs[tid] = s; rq[tid] = s2;
    __syncthreads();
    for (int off = 128; off > 0; off >>= 1) {
        if (tid < off) { rs[tid] += rs[tid + off]; rq[tid] += rq[tid + off]; }
        __syncthreads();
    }
    if (tid == 0) {
        float mean = rs[0] * (1.f / 65536.f);
        float var  = rq[0] * (1.f / 65536.f) - mean * mean;
        float sc = rsqrtf(var + 1e-5f) * gamma[o];
        scale[o] = sc;
        shift[o] = beta[o] - mean * sc;
    }
}

// ---------------------------------------------------------------------------
// Kernel 6: in-place normalize + ReLU on d_out (f32), 4 elems/thread
__global__ void k_norm(float* __restrict__ xb, const float* __restrict__ scale,
                       const float* __restrict__ shift) {
    int base = (blockIdx.x * 256 + threadIdx.x) * 4;
    int o = (base >> 14) & 255;
    float sc = scale[o], sh = shift[o];
    float4 v = *reinterpret_cast<const float4*>(xb + base);
    v.x = fmaxf(v.x * sc + sh, 0.f);
    v.y = fmaxf(v.y * sc + sh, 0.f);
    v.z = fmaxf(v.z * sc + sh, 0.f);
    v.w = fmaxf(v.w * sc + sh, 0.f);
    *reinterpret_cast<float4*>(xb + base) = v;
}

// ---------------------------------------------------------------------------
extern "C" void kernel_launch(void* const* d_in, const int* in_sizes, int n_in,
                              void* d_out, int out_size, void* d_ws, size_t ws_size,
                              hipStream_t stream) {
    // input order (all float32): low_feature(unused), high_feature, w_cc, b_cc,
    //   w_ce, b_ce, w_conv2, b_conv2, w_bott, gamma, beta
    const float* high    = (const float*)d_in[1];
    const float* w_cc    = (const float*)d_in[2];
    const float* b_cc    = (const float*)d_in[3];
    const float* w_ce    = (const float*)d_in[4];
    const float* b_ce    = (const float*)d_in[5];
    const float* w_conv2 = (const float*)d_in[6];
    const float* b_conv2 = (const float*)d_in[7];
    const float* w_bott  = (const float*)d_in[8];
    const float* gamma   = (const float*)d_in[9];
    const float* beta    = (const float*)d_in[10];

    char* ws = (char*)d_ws;
    float* Weff  = (float*)(ws + 0);          // 65536 f32
    float* beff  = (float*)(ws + 262144);     // 256 f32
    float* scale = (float*)(ws + 263168);     // 256 f32
    float* shift = (float*)(ws + 264192);     // 256 f32
    float* comp  = (float*)(ws + 265216);     // 4*64*4096 f32 = 4 MiB
    float* mask  = (float*)(ws + 4459520);    // 4*100*4096 f32 = 6.25 MiB
    float* Y     = (float*)(ws + 11013120);   // 4*256*4096 f32 = 16 MiB -> ends ~26.5 MiB
    float* xout  = (float*)d_out;             // pre-BN x in d_out, normalized in place

    k_weff    <<<256, 256, 0, stream>>>(w_bott, w_conv2, b_conv2, Weff, beff);
    k_compress<<<dim3(16, 4, 4), 256, 0, stream>>>(high, w_cc, b_cc, comp);
    k_encode  <<<256, 256, 0, stream>>>(comp, w_ce, b_ce, mask);
    k_ygemm   <<<dim3(64, 4, 4), 256, 0, stream>>>(Weff, high, Y);
    k_carafe  <<<256, 256, 0, stream>>>(Y, mask, beff, xout);
    k_stats   <<<256, 256, 0, stream>>>(xout, gamma, beta, scale, shift);
    k_norm    <<<16384, 256, 0, stream>>>(xout, scale, shift);
}